// Round 8
// baseline (85.805 us; speedup 1.0000x reference)
//
#include <hip/hip_runtime.h>
#include <hip/hip_bf16.h>

#define NFFT    512
#define HOPSZ   128
#define FBINS   257
#define TFR     2048
#define NBC     32            // B*C
#define OUTLEN  262016        // (T-1)*HOP
#define SPAD    256           // n_fft/2 (center trim)

typedef __bf16 bf16x8 __attribute__((ext_vector_type(8)));
typedef float  f32x4  __attribute__((ext_vector_type(4)));

static __device__ __forceinline__ float bf2f(unsigned short u) {
    union { unsigned int i; float f; } x; x.i = (unsigned int)u << 16; return x.f;
}

__device__ __forceinline__ void gld_lds16(const void* g, void* l) {
    __builtin_amdgcn_global_load_lds(
        (const __attribute__((address_space(1))) unsigned int*)g,
        (__attribute__((address_space(3))) unsigned int*)l, 16, 0, 0);
}

// ---------------------------------------------------------------------------
// Kernel 1: W' in MFMA A-fragment order (verified R2-R7).
//   Wf[(ks*32 + rt)*64 + lane]: 8 bf16, elem j:
//     n = rt*16 + (lane&15),  k = ks*32 + 4*(lane>>4) + (j&3) + 16*(j>>2)
// ---------------------------------------------------------------------------
__global__ __launch_bounds__(256) void k_wgen(const float* __restrict__ wnd,
                                              uint4* __restrict__ Wf) {
    const int gid  = blockIdx.x * 256 + threadIdx.x;   // < 34816
    const int lane = gid & 63;
    const int rt   = (gid >> 6) & 31;
    const int ks   = gid >> 11;
    const int n    = rt * 16 + (lane & 15);
    const int kb   = ks * 32 + ((lane >> 4) << 2);
    const float wn = wnd[n] * (1.0f / 512.0f);
    union { uint4 u; unsigned short h[8]; } o;
    #pragma unroll
    for (int j = 0; j < 8; ++j) {
        const int k = kb + (j & 3) + 16 * (j >> 2);
        float val = 0.0f;
        if (k < 2 * FBINS) {
            const int f = k >> 1;
            const bool edge = (f == 0) || (f == 256);
            const float cf = edge ? 1.0f : 2.0f;
            const int m = (f * n) & (NFFT - 1);
            const float ang = (float)m * 0.01227184630308513f; // 2*pi/512
            float s, c;
            __sincosf(ang, &s, &c);
            val = (k & 1) ? (edge ? 0.0f : -cf * wn * s) : (cf * wn * c);
        }
        __hip_bfloat16 hb = __float2bfloat16(val);
        o.h[j] = *(unsigned short*)&hb;
    }
    Wf[gid] = o.u;
}

// ---------------------------------------------------------------------------
// Kernel 2: frames(k<512) = W'[:, :512] @ X.
//   R7 macro-shape (BM=512: X read once; BT=64; 8 waves) + T3-minimum
//   pipeline: dbuf A(2x32K via global_load_lds) + dbuf B(2x8K), 16 periods
//   of BK=32, ONE __syncthreads per period, staging for ks+1 issued BEFORE
//   compute(ks) so the barrier drain is covered by ~16 MFMA + 8 ds_read.
//   All f-rows < 256 -> zero conditionals in the loop (DC k=512 in k_ola).
// ---------------------------------------------------------------------------
__global__ __launch_bounds__(512, 4) void k_mm(
    const float* __restrict__ X,
    const uint4* __restrict__ Wf,
    __hip_bfloat16* __restrict__ frames)
{
    __shared__ uint4 Ab[2][32][64];   // [buf][rt][lane] 64 KB
    __shared__ uint4 Bb[2][4][4][16]; // [buf][q][tile][slot] 8 KB

    const int tid  = threadIdx.x;
    const int lane = tid & 63;
    const int w    = tid >> 6;        // wave -> rows [64w, +64)
    const int q    = lane >> 4;
    const int rlo  = lane & 15;

    const int bid = blockIdx.x;       // 1024 = 8 XCD-chunks of 128
    const int id  = (bid & 7) * 128 + (bid >> 3);
    const int bc  = id >> 5;          // 0..31
    const int t0b = (id & 31) << 6;   // 64-t panel

    const float2* __restrict__ X2 = (const float2*)X + (size_t)bc * FBINS * TFR;

    // B staging role: sf = f_local 0..15, stt = t 0..31 (t = stt + 32d)
    const int sf  = tid >> 5;
    const int stt = tid & 31;
    const int sq  = ((2 * sf) & 15) >> 2;       // frag quarter
    const int sjw = (sf & 1) + 2 * (sf >> 3);   // u32 word within uint4
    unsigned int* __restrict__ BbU = (unsigned int*)Bb;

    f32x4  acc[4][4] = {};
    float2 xvA[2], xvB[2];

    auto issueA = [&](int ks, int buf) {        // 4x global_load_lds dwordx4
        const uint4* src = Wf + (size_t)ks * 2048;
        uint4* dst = &Ab[buf][0][0];
        #pragma unroll
        for (int r = 0; r < 4; ++r)
            gld_lds16(src + r * 512 + tid, dst + r * 512 + tid);
    };
    auto issueB = [&](int ks, float2* xv) {     // 2x 8B loads (f always <256)
        const float2* xb = X2 + (size_t)(ks * 16 + sf) * TFR + t0b + stt;
        xv[0] = xb[0];
        xv[1] = xb[32];
    };
    auto packB = [&](int buf, float2* xv) {     // cvt + 2x b32 LDS writes
        #pragma unroll
        for (int d = 0; d < 2; ++d) {
            union { unsigned int u; __hip_bfloat16 h[2]; } p;
            p.h[0] = __float2bfloat16(xv[d].x);
            p.h[1] = __float2bfloat16(xv[d].y);
            const int tile = (stt >> 4) + 2 * d;
            BbU[((((buf * 4 + sq) * 4 + tile) * 16) + (stt & 15)) * 4 + sjw] = p.u;
        }
    };
    auto compute = [&](int buf) {
        uint4 a[4], b[4];
        #pragma unroll
        for (int ni = 0; ni < 4; ++ni) b[ni] = Bb[buf][q][ni][rlo];
        #pragma unroll
        for (int mi = 0; mi < 4; ++mi) a[mi] = Ab[buf][4 * w + mi][lane];
        #pragma unroll
        for (int mi = 0; mi < 4; ++mi)
            #pragma unroll
            for (int ni = 0; ni < 4; ++ni)
                acc[mi][ni] = __builtin_amdgcn_mfma_f32_16x16x32_bf16(
                    __builtin_bit_cast(bf16x8, a[mi]),
                    __builtin_bit_cast(bf16x8, b[ni]), acc[mi][ni], 0, 0, 0);
    };

    // prologue: stage period 0 into buf 0
    issueB(0, xvA);
    issueA(0, 0);
    packB(0, xvA);                 // waits only on B's 2 loads (issued first)
    __syncthreads();               // drains A0 DMA

    #pragma unroll
    for (int ks = 0; ks < 16; ++ks) {
        const int cur = ks & 1;
        if (ks < 15) {
            if (ks & 1) issueB(ks + 1, xvA); else issueB(ks + 1, xvB);
            issueA(ks + 1, cur ^ 1);
        }
        compute(cur);
        if (ks < 15) {
            if (ks & 1) packB(cur ^ 1, xvA); else packB(cur ^ 1, xvB);
            __syncthreads();       // drain covered by the 16 MFMA above
        }
    }

    // epilogue: C/D row=(l>>4)*4+reg -> n, col=l&15 -> t (verified R1-R7)
    unsigned short* fb = (unsigned short*)frames;
    #pragma unroll
    for (int mi = 0; mi < 4; ++mi) {
        const int nbase = (w << 6) + (mi << 4) + (q << 2);
        #pragma unroll
        for (int ni = 0; ni < 4; ++ni) {
            const int t = t0b + ni * 16 + rlo;
            union { ushort4 u; __hip_bfloat16 hh[4]; } pk;
            pk.hh[0] = __float2bfloat16(acc[mi][ni][0]);
            pk.hh[1] = __float2bfloat16(acc[mi][ni][1]);
            pk.hh[2] = __float2bfloat16(acc[mi][ni][2]);
            pk.hh[3] = __float2bfloat16(acc[mi][ni][3]);
            *(ushort4*)(fb + (((size_t)(bc * TFR + t)) << 9) + nbase) = pk.u;
        }
    }
}

// ---------------------------------------------------------------------------
// Kernel 3: overlap-add + envelope normalize + the k=512 DC term (R5-R7-
//   verified).  W'[n][512] = wnd[n]*(1/512)*(-1)^n; contrib = that * re(X[256,t]).
// ---------------------------------------------------------------------------
__global__ __launch_bounds__(256) void k_ola(
    const __hip_bfloat16* __restrict__ frames,
    const float* __restrict__ wnd,
    const float* __restrict__ X,
    float* __restrict__ out)
{
    const int bc = blockIdx.y;
    const int o  = (blockIdx.x * 256 + threadIdx.x) * 4;
    if (o >= OUTLEN) return;
    const int s   = o + SPAD;
    const int tb_ = s >> 7;
    const int nb  = s & (HOPSZ - 1);
    const unsigned short* fb = (const unsigned short*)frames + (size_t)bc * TFR * NFFT;
    const float* Xre = X + (((size_t)bc * FBINS + 256) * TFR) * 2;  // re at [2t]
    const float sA = ((nb & 1) ? -1.0f : 1.0f) * (1.0f / 512.0f);
    float y0 = 0.f, y1 = 0.f, y2 = 0.f, y3 = 0.f;
    float e0 = 0.f, e1 = 0.f, e2 = 0.f, e3 = 0.f;
    #pragma unroll
    for (int r = 0; r < 4; ++r) {
        const int t = tb_ - r;
        if ((unsigned)t > (unsigned)(TFR - 1)) continue;
        const int n = nb + (r << 7);
        ushort4 v = *(const ushort4*)(fb + (size_t)t * NFFT + n);
        float4  wv = *(const float4*)(wnd + n);
        const float c = sA * Xre[2 * t];
        y0 += bf2f(v.x) + c * wv.x; e0 += wv.x * wv.x;
        y1 += bf2f(v.y) - c * wv.y; e1 += wv.y * wv.y;
        y2 += bf2f(v.z) + c * wv.z; e2 += wv.z * wv.z;
        y3 += bf2f(v.w) - c * wv.w; e3 += wv.w * wv.w;
    }
    float4 res = make_float4(y0 / e0, y1 / e1, y2 / e2, y3 / e3);
    *(float4*)(out + (size_t)bc * OUTLEN + o) = res;
}

// ---------------------------------------------------------------------------
extern "C" void kernel_launch(void* const* d_in, const int* in_sizes, int n_in,
                              void* d_out, int out_size, void* d_ws, size_t ws_size,
                              hipStream_t stream) {
    (void)in_sizes; (void)n_in; (void)out_size; (void)ws_size;
    const float* X   = (const float*)d_in[0];
    const float* wnd = (const float*)d_in[1];
    float* out = (float*)d_out;

    uint4* Wf = (uint4*)d_ws;                                            // 544 KB
    __hip_bfloat16* frames = (__hip_bfloat16*)((char*)d_ws + (1 << 20)); // 64 MB

    k_wgen<<<136, 256, 0, stream>>>(wnd, Wf);
    k_mm<<<1024, 512, 0, stream>>>(X, Wf, frames);
    k_ola<<<dim3((OUTLEN / 4 + 255) / 256, NBC), 256, 0, stream>>>(frames, wnd, X, out);
}

// Round 9
// 82.510 us; speedup vs baseline: 1.0399x; 1.0399x over previous
//
#include <hip/hip_runtime.h>
#include <hip/hip_bf16.h>

#define NFFT    512
#define HOPSZ   128
#define FBINS   257
#define TFR     2048
#define NBC     32            // B*C
#define OUTLEN  262016        // (T-1)*HOP
#define SPAD    256           // n_fft/2 (center trim)

typedef __bf16 bf16x8 __attribute__((ext_vector_type(8)));
typedef float  f32x4  __attribute__((ext_vector_type(4)));

static __device__ __forceinline__ float bf2f(unsigned short u) {
    union { unsigned int i; float f; } x; x.i = (unsigned int)u << 16; return x.f;
}

__device__ __forceinline__ void gld_lds16(const void* g, void* l) {
    __builtin_amdgcn_global_load_lds(
        (const __attribute__((address_space(1))) unsigned int*)g,
        (__attribute__((address_space(3))) unsigned int*)l, 16, 0, 0);
}

// ---------------------------------------------------------------------------
// Kernel 1: W' in MFMA A-fragment order (verified R2-R8).
//   Wf[(ks*32 + rt)*64 + lane]: 8 bf16, elem j:
//     n = rt*16 + (lane&15),  k = ks*32 + 4*(lane>>4) + (j&3) + 16*(j>>2)
// ---------------------------------------------------------------------------
__global__ __launch_bounds__(256) void k_wgen(const float* __restrict__ wnd,
                                              uint4* __restrict__ Wf) {
    const int gid  = blockIdx.x * 256 + threadIdx.x;   // < 34816
    const int lane = gid & 63;
    const int rt   = (gid >> 6) & 31;
    const int ks   = gid >> 11;
    const int n    = rt * 16 + (lane & 15);
    const int kb   = ks * 32 + ((lane >> 4) << 2);
    const float wn = wnd[n] * (1.0f / 512.0f);
    union { uint4 u; unsigned short h[8]; } o;
    #pragma unroll
    for (int j = 0; j < 8; ++j) {
        const int k = kb + (j & 3) + 16 * (j >> 2);
        float val = 0.0f;
        if (k < 2 * FBINS) {
            const int f = k >> 1;
            const bool edge = (f == 0) || (f == 256);
            const float cf = edge ? 1.0f : 2.0f;
            const int m = (f * n) & (NFFT - 1);
            const float ang = (float)m * 0.01227184630308513f; // 2*pi/512
            float s, c;
            __sincosf(ang, &s, &c);
            val = (k & 1) ? (edge ? 0.0f : -cf * wn * s) : (cf * wn * c);
        }
        __hip_bfloat16 hb = __float2bfloat16(val);
        o.h[j] = *(unsigned short*)&hb;
    }
    Wf[gid] = o.u;
}

// ---------------------------------------------------------------------------
// Kernel 2: frames(k<512) = W'[:, :512] @ X.
//   GEOMETRY FIX: BM=256, BN=128, BK=32 -> staging demand 39.6 B/cyc/CU
//   (vs 58-66 in R1/R7/R8, which exceeded DMA supply and pinned MfmaUtil
//   at ~14%). acc[4][4]=64 VGPR keeps <=128 -> 2 blocks x 8 waves = 16
//   waves/CU. dbuf A(2x16K DMA) + B(2x8K reg-staged) = 48 KB.
//   1024 blocks: id XCD-chunked, M-pair (m=id&1) adjacent -> shares X panel
//   in L2. X read 2x chip-wide but L3-resident (R7: FETCH 70MB << X 135MB).
//   Schedule: R8's single barrier per period (numerics verified).
// ---------------------------------------------------------------------------
__global__ __launch_bounds__(512, 4) void k_mm(
    const float* __restrict__ X,
    const uint4* __restrict__ Wf,
    __hip_bfloat16* __restrict__ frames)
{
    __shared__ uint4 Ab[2][1024];     // 2 x 16 KB  [buf][rt*64+lane]
    __shared__ uint4 Bb[2][4][128];   // 2 x  8 KB  [buf][q][t]

    const int tid  = threadIdx.x;
    const int lane = tid & 63;
    const int w    = tid >> 6;        // 0..7
    const int wr   = w >> 1;          // row-group 0..3 (64 rows)
    const int wc   = w & 1;           // col-group 0..1 (64 t)
    const int q    = lane >> 4;
    const int rlo  = lane & 15;

    const int bid = blockIdx.x;       // 1024 = 8 XCD-chunks of 128
    const int id  = (bid & 7) * 128 + (bid >> 3);
    const int m     = id & 1;         // M-half: rows [256m, +256)
    const int pair  = id >> 1;
    const int panel = pair & 15;      // 128-t panel
    const int bc    = pair >> 4;      // 0..31
    const int t0b   = panel << 7;

    const float2* __restrict__ X2 = (const float2*)X + (size_t)bc * FBINS * TFR;

    // B staging role: p = f-pair 0..7 (f = 2p, 2p+1), st = t 0..63 (t, t+64)
    const int p  = tid >> 6;
    const int st = tid & 63;
    const int sq = p & 3;             // frag quarter
    const int sh = p >> 2;            // frag half (k<16 / k>=16)

    f32x4  acc[4][4] = {};
    float2 xv[2][4];                  // [pingpong][d]; static idx after unroll

    auto issueA = [&](int ks, int buf) {       // 2x global_load_lds dwordx4
        const uint4* src = Wf + (size_t)ks * 2048 + m * 1024;
        gld_lds16(src + tid,       &Ab[buf][tid]);
        gld_lds16(src + 512 + tid, &Ab[buf][512 + tid]);
    };
    auto issueB = [&](int ks, float2 (&bx)[4]) {   // 4x 8B loads, coalesced
        const float2* xb = X2 + (size_t)(ks * 16 + 2 * p) * TFR + t0b + st;
        bx[0] = xb[0];                 // f=2p,   t=st
        bx[1] = xb[TFR];               // f=2p+1, t=st
        bx[2] = xb[64];                // f=2p,   t=st+64
        bx[3] = xb[TFR + 64];          // f=2p+1, t=st+64
    };
    auto packB = [&](int buf, float2 (&bx)[4]) {   // cvt + 2x ds_write_b64
        union { uint2 u; __hip_bfloat16 hh[4]; } p0, p1;
        p0.hh[0] = __float2bfloat16(bx[0].x); p0.hh[1] = __float2bfloat16(bx[0].y);
        p0.hh[2] = __float2bfloat16(bx[1].x); p0.hh[3] = __float2bfloat16(bx[1].y);
        p1.hh[0] = __float2bfloat16(bx[2].x); p1.hh[1] = __float2bfloat16(bx[2].y);
        p1.hh[2] = __float2bfloat16(bx[3].x); p1.hh[3] = __float2bfloat16(bx[3].y);
        ((uint2*)&Bb[buf][sq][st])[sh]      = p0.u;
        ((uint2*)&Bb[buf][sq][st + 64])[sh] = p1.u;
    };
    auto compute = [&](int buf) {
        uint4 a[4], b[4];
        #pragma unroll
        for (int ni = 0; ni < 4; ++ni) b[ni] = Bb[buf][q][wc * 64 + ni * 16 + rlo];
        #pragma unroll
        for (int mi = 0; mi < 4; ++mi) a[mi] = Ab[buf][(4 * wr + mi) * 64 + lane];
        #pragma unroll
        for (int mi = 0; mi < 4; ++mi)
            #pragma unroll
            for (int ni = 0; ni < 4; ++ni)
                acc[mi][ni] = __builtin_amdgcn_mfma_f32_16x16x32_bf16(
                    __builtin_bit_cast(bf16x8, a[mi]),
                    __builtin_bit_cast(bf16x8, b[ni]), acc[mi][ni], 0, 0, 0);
    };

    // prologue: stage period 0 into buf 0
    issueB(0, xv[0]);
    issueA(0, 0);
    packB(0, xv[0]);               // compiler waits only on the 4 B loads
    __syncthreads();               // drains A0 DMA

    #pragma unroll
    for (int ks = 0; ks < 16; ++ks) {
        const int cur = ks & 1;
        if (ks < 15) {
            issueB(ks + 1, xv[(ks + 1) & 1]);
            issueA(ks + 1, cur ^ 1);
        }
        compute(cur);
        if (ks < 15) {
            packB(cur ^ 1, xv[(ks + 1) & 1]);
            __syncthreads();       // drain covered by 16 MFMA + next block's work
        }
    }

    // epilogue: C/D row=(l>>4)*4+reg -> n, col=l&15 -> t (verified R1-R8)
    unsigned short* fb = (unsigned short*)frames;
    #pragma unroll
    for (int mi = 0; mi < 4; ++mi) {
        const int nbase = m * 256 + wr * 64 + mi * 16 + (q << 2);
        #pragma unroll
        for (int ni = 0; ni < 4; ++ni) {
            const int t = t0b + wc * 64 + ni * 16 + rlo;
            union { ushort4 u; __hip_bfloat16 hh[4]; } pk;
            pk.hh[0] = __float2bfloat16(acc[mi][ni][0]);
            pk.hh[1] = __float2bfloat16(acc[mi][ni][1]);
            pk.hh[2] = __float2bfloat16(acc[mi][ni][2]);
            pk.hh[3] = __float2bfloat16(acc[mi][ni][3]);
            *(ushort4*)(fb + (((size_t)(bc * TFR + t)) << 9) + nbase) = pk.u;
        }
    }
}

// ---------------------------------------------------------------------------
// Kernel 3: overlap-add + envelope normalize + the k=512 DC term (R5-R8-
//   verified).  W'[n][512] = wnd[n]*(1/512)*(-1)^n; contrib = that * re(X[256,t]).
// ---------------------------------------------------------------------------
__global__ __launch_bounds__(256) void k_ola(
    const __hip_bfloat16* __restrict__ frames,
    const float* __restrict__ wnd,
    const float* __restrict__ X,
    float* __restrict__ out)
{
    const int bc = blockIdx.y;
    const int o  = (blockIdx.x * 256 + threadIdx.x) * 4;
    if (o >= OUTLEN) return;
    const int s   = o + SPAD;
    const int tb_ = s >> 7;
    const int nb  = s & (HOPSZ - 1);
    const unsigned short* fb = (const unsigned short*)frames + (size_t)bc * TFR * NFFT;
    const float* Xre = X + (((size_t)bc * FBINS + 256) * TFR) * 2;  // re at [2t]
    const float sA = ((nb & 1) ? -1.0f : 1.0f) * (1.0f / 512.0f);
    float y0 = 0.f, y1 = 0.f, y2 = 0.f, y3 = 0.f;
    float e0 = 0.f, e1 = 0.f, e2 = 0.f, e3 = 0.f;
    #pragma unroll
    for (int r = 0; r < 4; ++r) {
        const int t = tb_ - r;
        if ((unsigned)t > (unsigned)(TFR - 1)) continue;
        const int n = nb + (r << 7);
        ushort4 v = *(const ushort4*)(fb + (size_t)t * NFFT + n);
        float4  wv = *(const float4*)(wnd + n);
        const float c = sA * Xre[2 * t];
        y0 += bf2f(v.x) + c * wv.x; e0 += wv.x * wv.x;
        y1 += bf2f(v.y) - c * wv.y; e1 += wv.y * wv.y;
        y2 += bf2f(v.z) + c * wv.z; e2 += wv.z * wv.z;
        y3 += bf2f(v.w) - c * wv.w; e3 += wv.w * wv.w;
    }
    float4 res = make_float4(y0 / e0, y1 / e1, y2 / e2, y3 / e3);
    *(float4*)(out + (size_t)bc * OUTLEN + o) = res;
}

// ---------------------------------------------------------------------------
extern "C" void kernel_launch(void* const* d_in, const int* in_sizes, int n_in,
                              void* d_out, int out_size, void* d_ws, size_t ws_size,
                              hipStream_t stream) {
    (void)in_sizes; (void)n_in; (void)out_size; (void)ws_size;
    const float* X   = (const float*)d_in[0];
    const float* wnd = (const float*)d_in[1];
    float* out = (float*)d_out;

    uint4* Wf = (uint4*)d_ws;                                            // 544 KB
    __hip_bfloat16* frames = (__hip_bfloat16*)((char*)d_ws + (1 << 20)); // 64 MB

    k_wgen<<<136, 256, 0, stream>>>(wnd, Wf);
    k_mm<<<1024, 512, 0, stream>>>(X, Wf, frames);
    k_ola<<<dim3((OUTLEN / 4 + 255) / 256, NBC), 256, 0, stream>>>(frames, wnd, X, out);
}

// Round 10
// 81.653 us; speedup vs baseline: 1.0508x; 1.0105x over previous
//
#include <hip/hip_runtime.h>
#include <hip/hip_bf16.h>

#define NFFT    512
#define HOPSZ   128
#define FBINS   257
#define TFR     2048
#define NBC     32            // B*C
#define OUTLEN  262016        // (T-1)*HOP
#define SPAD    256           // n_fft/2 (center trim)

typedef __bf16 bf16x8 __attribute__((ext_vector_type(8)));
typedef float  f32x4  __attribute__((ext_vector_type(4)));

static __device__ __forceinline__ float bf2f(unsigned short u) {
    union { unsigned int i; float f; } x; x.i = (unsigned int)u << 16; return x.f;
}

__device__ __forceinline__ void gld_lds16(const void* g, void* l) {
    __builtin_amdgcn_global_load_lds(
        (const __attribute__((address_space(1))) unsigned int*)g,
        (__attribute__((address_space(3))) unsigned int*)l, 16, 0, 0);
}

// ---------------------------------------------------------------------------
// Kernel 1: W' in MFMA A-fragment order (verified R2-R9).
//   Wf[(ks*32 + rt)*64 + lane]: 8 bf16, elem j:
//     n = rt*16 + (lane&15),  k = ks*32 + 4*(lane>>4) + (j&3) + 16*(j>>2)
// ---------------------------------------------------------------------------
__global__ __launch_bounds__(256) void k_wgen(const float* __restrict__ wnd,
                                              uint4* __restrict__ Wf) {
    const int gid  = blockIdx.x * 256 + threadIdx.x;   // < 34816
    const int lane = gid & 63;
    const int rt   = (gid >> 6) & 31;
    const int ks   = gid >> 11;
    const int n    = rt * 16 + (lane & 15);
    const int kb   = ks * 32 + ((lane >> 4) << 2);
    const float wn = wnd[n] * (1.0f / 512.0f);
    union { uint4 u; unsigned short h[8]; } o;
    #pragma unroll
    for (int j = 0; j < 8; ++j) {
        const int k = kb + (j & 3) + 16 * (j >> 2);
        float val = 0.0f;
        if (k < 2 * FBINS) {
            const int f = k >> 1;
            const bool edge = (f == 0) || (f == 256);
            const float cf = edge ? 1.0f : 2.0f;
            const int m = (f * n) & (NFFT - 1);
            const float ang = (float)m * 0.01227184630308513f; // 2*pi/512
            float s, c;
            __sincosf(ang, &s, &c);
            val = (k & 1) ? (edge ? 0.0f : -cf * wn * s) : (cf * wn * c);
        }
        __hip_bfloat16 hb = __float2bfloat16(val);
        o.h[j] = *(unsigned short*)&hb;
    }
    Wf[gid] = o.u;
}

// ---------------------------------------------------------------------------
// Kernel 2: frames(k<512) = W'[:, :512] @ X — m97-faithful structure.
//   2048 blocks x 256 thr (4 waves). Block: 256 rows (m=id&1) x 64 t.
//   SINGLE-buffered LDS (24 KB) -> many INDEPENDENT-phase blocks/CU; the
//   period is self-contained: {sync; stage A+B via global_load_lds; sync;
//   compute}. Other resident blocks fill each other's stage drains (m114).
//   B staged as RAW fp32 (no cvt/ds_write/reg roundtrip); fp32->bf16 at
//   frag-read, overlapped with MFMA. acc[4][4]=64 VGPR, cap 128 (4 w/SIMD).
// ---------------------------------------------------------------------------
__global__ __launch_bounds__(256, 4) void k_mm(
    const float* __restrict__ X,
    const uint4* __restrict__ Wf,
    __hip_bfloat16* __restrict__ frames)
{
    __shared__ uint4  Ab[1024];       // 16 KB: A slab, fragment order
    __shared__ float2 Bf[16][64];     //  8 KB: [f_local][t] raw fp32

    const int tid  = threadIdx.x;
    const int lane = tid & 63;
    const int w    = tid >> 6;        // wave 0..3 -> rows [64w,+64)
    const int q    = lane >> 4;
    const int rlo  = lane & 15;

    const int bid = blockIdx.x;       // 2048 = 8 XCD-chunks of 256
    const int id  = (bid & 7) * 256 + (bid >> 3);
    const int m     = id & 1;         // M-half: rows [256m,+256)
    const int panel = (id >> 1) & 31; // 64-t panel
    const int bc    = id >> 6;        // 0..31
    const int t0b   = panel << 6;

    const float2* __restrict__ X2 = (const float2*)X + (size_t)bc * FBINS * TFR;

    // staging roles
    const int br = tid >> 5;          // B row 0..7 (also +8)
    const int bck = tid & 31;         // B 16B-chunk within row

    f32x4 acc[4][4] = {};

    for (int ks = 0; ks < 16; ++ks) {
        __syncthreads();              // LDS free (prev compute done)
        // ---- stage A: 4x gld_lds (16 KB slab, fragment-ordered) ----
        const uint4* asrc = Wf + (size_t)ks * 2048 + m * 1024;
        #pragma unroll
        for (int r = 0; r < 4; ++r)
            gld_lds16(asrc + r * 256 + tid, &Ab[r * 256 + tid]);
        // ---- stage B: 2x gld_lds (8 KB, raw fp32 rows) ----
        {
            const float2* b0 = X2 + (size_t)(ks * 16 + br) * TFR + t0b + 2 * bck;
            gld_lds16(b0,                    &Bf[br][2 * bck]);
            gld_lds16(b0 + (size_t)8 * TFR,  &Bf[br + 8][2 * bck]);
        }
        __syncthreads();              // drains DMA (compiler: vmcnt(0))
        // ---- compute: 16 MFMA / wave ----
        uint4 a[4], b[4];
        #pragma unroll
        for (int ni = 0; ni < 4; ++ni) {
            const float2* Bp = &Bf[2 * q][ni * 16 + rlo];
            float2 v0 = Bp[0];
            float2 v1 = Bp[64];       // f = 2q+1
            float2 v2 = Bp[8 * 64];   // f = 2q+8
            float2 v3 = Bp[9 * 64];   // f = 2q+9
            union { unsigned short h[8]; uint4 u; } pk;
            __hip_bfloat16 t;
            t = __float2bfloat16(v0.x); pk.h[0] = *(unsigned short*)&t;
            t = __float2bfloat16(v0.y); pk.h[1] = *(unsigned short*)&t;
            t = __float2bfloat16(v1.x); pk.h[2] = *(unsigned short*)&t;
            t = __float2bfloat16(v1.y); pk.h[3] = *(unsigned short*)&t;
            t = __float2bfloat16(v2.x); pk.h[4] = *(unsigned short*)&t;
            t = __float2bfloat16(v2.y); pk.h[5] = *(unsigned short*)&t;
            t = __float2bfloat16(v3.x); pk.h[6] = *(unsigned short*)&t;
            t = __float2bfloat16(v3.y); pk.h[7] = *(unsigned short*)&t;
            b[ni] = pk.u;
        }
        #pragma unroll
        for (int mi = 0; mi < 4; ++mi) a[mi] = Ab[(4 * w + mi) * 64 + lane];
        #pragma unroll
        for (int mi = 0; mi < 4; ++mi)
            #pragma unroll
            for (int ni = 0; ni < 4; ++ni)
                acc[mi][ni] = __builtin_amdgcn_mfma_f32_16x16x32_bf16(
                    __builtin_bit_cast(bf16x8, a[mi]),
                    __builtin_bit_cast(bf16x8, b[ni]), acc[mi][ni], 0, 0, 0);
    }

    // epilogue: C/D row=(l>>4)*4+reg -> n, col=l&15 -> t (verified R1-R9)
    unsigned short* fb = (unsigned short*)frames;
    #pragma unroll
    for (int mi = 0; mi < 4; ++mi) {
        const int nbase = m * 256 + (w << 6) + (mi << 4) + (q << 2);
        #pragma unroll
        for (int ni = 0; ni < 4; ++ni) {
            const int t = t0b + ni * 16 + rlo;
            union { ushort4 u; __hip_bfloat16 hh[4]; } pk;
            pk.hh[0] = __float2bfloat16(acc[mi][ni][0]);
            pk.hh[1] = __float2bfloat16(acc[mi][ni][1]);
            pk.hh[2] = __float2bfloat16(acc[mi][ni][2]);
            pk.hh[3] = __float2bfloat16(acc[mi][ni][3]);
            *(ushort4*)(fb + (((size_t)(bc * TFR + t)) << 9) + nbase) = pk.u;
        }
    }
}

// ---------------------------------------------------------------------------
// Kernel 3: overlap-add + envelope normalize + the k=512 DC term (R5-R9-
//   verified).  W'[n][512] = wnd[n]*(1/512)*(-1)^n; contrib = that * re(X[256,t]).
// ---------------------------------------------------------------------------
__global__ __launch_bounds__(256) void k_ola(
    const __hip_bfloat16* __restrict__ frames,
    const float* __restrict__ wnd,
    const float* __restrict__ X,
    float* __restrict__ out)
{
    const int bc = blockIdx.y;
    const int o  = (blockIdx.x * 256 + threadIdx.x) * 4;
    if (o >= OUTLEN) return;
    const int s   = o + SPAD;
    const int tb_ = s >> 7;
    const int nb  = s & (HOPSZ - 1);
    const unsigned short* fb = (const unsigned short*)frames + (size_t)bc * TFR * NFFT;
    const float* Xre = X + (((size_t)bc * FBINS + 256) * TFR) * 2;  // re at [2t]
    const float sA = ((nb & 1) ? -1.0f : 1.0f) * (1.0f / 512.0f);
    float y0 = 0.f, y1 = 0.f, y2 = 0.f, y3 = 0.f;
    float e0 = 0.f, e1 = 0.f, e2 = 0.f, e3 = 0.f;
    #pragma unroll
    for (int r = 0; r < 4; ++r) {
        const int t = tb_ - r;
        if ((unsigned)t > (unsigned)(TFR - 1)) continue;
        const int n = nb + (r << 7);
        ushort4 v = *(const ushort4*)(fb + (size_t)t * NFFT + n);
        float4  wv = *(const float4*)(wnd + n);
        const float c = sA * Xre[2 * t];
        y0 += bf2f(v.x) + c * wv.x; e0 += wv.x * wv.x;
        y1 += bf2f(v.y) - c * wv.y; e1 += wv.y * wv.y;
        y2 += bf2f(v.z) + c * wv.z; e2 += wv.z * wv.z;
        y3 += bf2f(v.w) - c * wv.w; e3 += wv.w * wv.w;
    }
    float4 res = make_float4(y0 / e0, y1 / e1, y2 / e2, y3 / e3);
    *(float4*)(out + (size_t)bc * OUTLEN + o) = res;
}

// ---------------------------------------------------------------------------
extern "C" void kernel_launch(void* const* d_in, const int* in_sizes, int n_in,
                              void* d_out, int out_size, void* d_ws, size_t ws_size,
                              hipStream_t stream) {
    (void)in_sizes; (void)n_in; (void)out_size; (void)ws_size;
    const float* X   = (const float*)d_in[0];
    const float* wnd = (const float*)d_in[1];
    float* out = (float*)d_out;

    uint4* Wf = (uint4*)d_ws;                                            // 544 KB
    __hip_bfloat16* frames = (__hip_bfloat16*)((char*)d_ws + (1 << 20)); // 64 MB

    k_wgen<<<136, 256, 0, stream>>>(wnd, Wf);
    k_mm<<<2048, 256, 0, stream>>>(X, Wf, frames);
    k_ola<<<dim3((OUTLEN / 4 + 255) / 256, NBC), 256, 0, stream>>>(frames, wnd, X, out);
}